// Round 9
// baseline (278.007 us; speedup 1.0000x reference)
//
#include <hip/hip_runtime.h>

#define S 16
#define D 64
#define G 16            // roots per k_root block (= one MFMA M-tile for Y)
#define PROWS 31        // G + S - 1 node rows per group
#define PSTR 68         // part row stride in dwords (16B-aligned rows for b128 RMW)
#define PREG 2176       // per-wave part region, dwords (>= 31*68, 16B-aligned)
#define XSTR 136        // x2x1 LDS row stride in bf16 (128 + 8 pad)
#define ZSTR 68         // k_linzout Z staging stride

typedef __attribute__((ext_vector_type(8))) short bf16x8;
typedef __attribute__((ext_vector_type(4))) float f32x4;

union BF8 { unsigned u[4]; bf16x8 v; };

// round-half-up f32->bf16 pack: LOW 16 = x, HIGH 16 = y
__device__ __forceinline__ unsigned pk2bf(float x, float y) {
    unsigned ux = __float_as_uint(x) + 0x8000u;
    unsigned uy = __float_as_uint(y) + 0x8000u;
    return __builtin_amdgcn_perm(uy, ux, 0x07060302);  // {lo: hi16(ux), hi: hi16(uy)}
}
__device__ __forceinline__ bf16x8 pk8(float a, float b, float c, float d,
                                      float e, float f, float g, float h) {
    BF8 t;
    t.u[0] = pk2bf(a, b); t.u[1] = pk2bf(c, d);
    t.u[2] = pk2bf(e, f); t.u[3] = pk2bf(g, h);
    return t.v;
}
// RNE (one-time weight prep only)
__device__ __forceinline__ short f2bf(float f) {
    unsigned u = __float_as_uint(f);
    u += 0x7fffu + ((u >> 16) & 1u);
    return (short)(u >> 16);
}

// ---- K_counts (+ fused weight prep in the first 16384 threads) ----
// Per-EDGE graph adjacency counts: Q[node] = 128-bit row, 4-bit field f
// (bit 4f of {lo,hi}) = count at delta = f - 16. Edge (u, u+delta):
// Qhi[u] field delta, Qlo[u+delta] field 16-delta. Each edge appears
// exactly once in the first half of the message list with msg_tgt%16==0
// (the root i == u instance): u = tgt>>4, delta = src&15.
// NOTE: WabT is stored with the K-dim INTERLEAVED: knew = 2e for X2 rows
// (e<64), knew = 2(e-64)+1 for X1 rows — matching x2x1's (X2,X1) pairs.
__global__ void k_counts(const int* __restrict__ msg_tgt, const int* __restrict__ msg_src,
                         unsigned long long* __restrict__ Q, int E2,
                         const float* __restrict__ W0, const float* __restrict__ W1,
                         unsigned short* __restrict__ W0T, unsigned short* __restrict__ WabT,
                         unsigned short* __restrict__ WcT) {
    int idx = blockIdx.x * 256 + threadIdx.x;
    if (idx < 4096) {
        int d = idx >> 6, k = idx & 63;
        W0T[d * 64 + k] = (unsigned short)f2bf(W0[k * 64 + d]);
    } else if (idx < 12288) {
        int o = idx - 4096; int d = o >> 7, e = o & 127;
        int knew = (e < 64) ? (2 * e) : (2 * (e - 64) + 1);
        WabT[d * 128 + knew] = (unsigned short)f2bf(W1[e * 64 + d]);
    } else if (idx < 16384) {
        int o = idx - 12288; int d = o >> 6, e = o & 63;
        WcT[d * 64 + e] = (unsigned short)f2bf(W1[(128 + e) * 64 + d]);
    }
    if (idx >= E2) return;
    int t = msg_tgt[idx];
    if (t & 15) return;                      // keep only the i==u instance
    int delta = msg_src[idx] & 15;           // v - u, in [1,15]
    int u = t >> 4;
    atomicAdd(&Q[2 * u + 1], 1ull << (4 * delta));
    atomicAdd(&Q[2 * (u + delta)], 1ull << (64 - 4 * delta));
}

// ---- K_root: one WAVE per root, 2-root software pipeline:
// issue bperms(g) -> full stage-1 of g+4 (X load + 8 MFMA + pack, hides the
// bperm round-trip) -> stage-2(g) + reduce + b128 RMW. Carried state is only
// hp/A2 double-buffers (persistent X copies eliminated: net -16 VGPR vs r8).
__global__ __launch_bounds__(256, 4) void k_root(
    const float* __restrict__ X, const float* __restrict__ b0,
    const unsigned short* __restrict__ W0T,
    const unsigned long long* __restrict__ Q,     // [N][2] packed 4-bit adjacency
    const unsigned short* __restrict__ WabT, const float* __restrict__ b1,
    float* __restrict__ Y, float* __restrict__ Qpart, int R)
{
    __shared__ float part[4 * PREG];               // 34816 B, per-wave private regions
    __shared__ unsigned short x2x1[G][XSTR];       // 4352 B
    int grp = blockIdx.x;
    int tid = threadIdx.x, lane = tid & 63, w = tid >> 6, m = lane & 15, q = lane >> 4;
    const ulonglong2* Q2 = (const ulonglong2*)Q;

    // zero own region: 8 x b128 + 1 x b64 (2176 dwords, private per wave)
    {
        float4 z = {0.f, 0.f, 0.f, 0.f};
#pragma unroll
        for (int i = 0; i < 8; i++)
            *(float4*)&part[w * PREG + i * 256 + lane * 4] = z;
        float2 z2 = {0.f, 0.f};
        *(float2*)&part[w * PREG + 2048 + lane * 2] = z2;
    }

    // stage-1 B fragments for all 4 column groups (resident in VGPRs)
    bf16x8 bB[8];
    float bv[4];
#pragma unroll
    for (int cg = 0; cg < 4; cg++) {
        const bf16x8* wr = (const bf16x8*)(W0T + (size_t)(cg * 16 + m) * 64);
        bB[cg * 2] = wr[q]; bB[cg * 2 + 1] = wr[4 + q];
        bv[cg] = b0[cg * 16 + m];
    }

    // hoisted bpermute byte-addresses for the stage-2 gather:
    // lane (q,m) pulls H rows 8q..8q+7 (col m) from lanes (2q,m),(2q+1,m) (mod 64)
    int bp0 = (((2 * q) * 16 + m) & 63) * 4;
    int bp1 = (((2 * q + 1) * 16 + m) & 63) * 4;

    int root0 = grp * G;
    int gmax = R - root0; if (gmax > G) gmax = G;
    const float* Xg = X + (size_t)root0 * S * D;

    // ---- stage-1 for one root: X load + 8 MFMA + pack + A2 funnel ----
    unsigned hpc0[4], hpc1[4]; bf16x8 A2c;
    auto stage1 = [&](int g, unsigned* h0, unsigned* h1, bf16x8& A2o) {
        const float* xr = Xg + ((size_t)g * S + m) * D + q * 8;
        float4 xa = *(const float4*)(xr);
        float4 xb = *(const float4*)(xr + 4);
        float4 xc = *(const float4*)(xr + 32);
        float4 xd = *(const float4*)(xr + 36);
        ulonglong2 qq = Q2[(size_t)(root0 + g) + m];   // node j = root + m
        bf16x8 a0 = pk8(xa.x, xa.y, xa.z, xa.w, xb.x, xb.y, xb.z, xb.w);
        bf16x8 a1 = pk8(xc.x, xc.y, xc.z, xc.w, xd.x, xd.y, xd.z, xd.w);
#pragma unroll
        for (int cg = 0; cg < 4; cg++) {
            f32x4 c = {bv[cg], bv[cg], bv[cg], bv[cg]};
            c = __builtin_amdgcn_mfma_f32_16x16x32_bf16(a0, bB[cg * 2], c, 0, 0, 0);
            c = __builtin_amdgcn_mfma_f32_16x16x32_bf16(a1, bB[cg * 2 + 1], c, 0, 0, 0);
            h0[cg] = pk2bf(fmaxf(c[0], 0.f), fmaxf(c[1], 0.f));
            h1[cg] = pk2bf(fmaxf(c[2], 0.f), fmaxf(c[3], 0.f));
        }
        // CNT fragment: row m, k = q*8+j (rows k>=16 zero); 128-bit funnel
        unsigned long long cw = (qq.y << (4 * m)) | ((qq.x >> (63 - 4 * m)) >> 1);
        unsigned w32 = (q == 0) ? (unsigned)cw : ((q == 1) ? (unsigned)(cw >> 32) : 0u);
        A2o = pk8((float)((w32 >> 0) & 15u),  (float)((w32 >> 4) & 15u),
                  (float)((w32 >> 8) & 15u),  (float)((w32 >> 12) & 15u),
                  (float)((w32 >> 16) & 15u), (float)((w32 >> 20) & 15u),
                  (float)((w32 >> 24) & 15u), (float)((w32 >> 28) & 15u));
    };

    if (w < gmax) stage1(w, hpc0, hpc1, A2c);

    for (int g = w; g < gmax; g += 4) {
        // phase B: issue ALL 16 bperms for root g
        BF8 b2[4];
#pragma unroll
        for (int cg = 0; cg < 4; cg++) {
            b2[cg].u[0] = __builtin_amdgcn_ds_bpermute(bp0, (int)hpc0[cg]);
            b2[cg].u[1] = __builtin_amdgcn_ds_bpermute(bp0, (int)hpc1[cg]);
            b2[cg].u[2] = __builtin_amdgcn_ds_bpermute(bp1, (int)hpc0[cg]);
            b2[cg].u[3] = __builtin_amdgcn_ds_bpermute(bp1, (int)hpc1[cg]);
        }

        // pipeline: full stage-1 of root g+4 (independent of the bperms above)
        int gn = g + 4;
        bool pf = (gn < gmax);
        unsigned hpn0[4], hpn1[4]; bf16x8 A2n;
        if (pf) stage1(gn, hpn0, hpn1, A2n);

        // phase C: swapped-operand MFMAs -> Xmp^T. Lane (q,m) reg r holds
        // Xmp[tuple row m][d = cg*16 + 4q + r]  (A2's zero k>=16 rows kill
        // the garbage in b2's A-interpretation lanes q>=2).
        f32x4 xmt[4];
#pragma unroll
        for (int cg = 0; cg < 4; cg++) {
            f32x4 z4 = {0.f, 0.f, 0.f, 0.f};
            xmt[cg] = __builtin_amdgcn_mfma_f32_16x16x32_bf16(b2[cg].v, A2c, z4, 0, 0, 0);
        }

        // phase D: unswapped MFMAs (MFMA pipe is idle) for the X2/X1 path:
        // lane (q,m) reg r = Xmp[q*4+r][cg*16+m]
        float ps[4], x1[4];
#pragma unroll
        for (int cg = 0; cg < 4; cg++) {
            f32x4 z4 = {0.f, 0.f, 0.f, 0.f};
            f32x4 xu = __builtin_amdgcn_mfma_f32_16x16x32_bf16(A2c, b2[cg].v, z4, 0, 0, 0);
            ps[cg] = (xu[0] + xu[1]) + (xu[2] + xu[3]);
            x1[cg] = xu[0];                       // Xmp[0][cg*16+m] valid at q==0
        }
#pragma unroll
        for (int cg = 0; cg < 4; cg++) ps[cg] += __shfl_xor(ps[cg], 16);
#pragma unroll
        for (int cg = 0; cg < 4; cg++) ps[cg] += __shfl_xor(ps[cg], 32);
        if (q == 0) {
#pragma unroll
            for (int cg = 0; cg < 4; cg++)   // interleaved pair: LOW=X2, HIGH=X1
                *(unsigned*)&x2x1[g][2 * (cg * 16 + m)] =
                    pk2bf(ps[cg] * (1.f / 16.f), x1[cg]);
        }

        // phase E (sink): per-cg b128 RMW — transient registers only
        float* pbase = &part[w * PREG + (g + m) * PSTR + 4 * q];
#pragma unroll
        for (int cg = 0; cg < 4; cg++) {
            float4 pr = *(float4*)&pbase[cg * 16];
            pr.x += xmt[cg][0]; pr.y += xmt[cg][1];
            pr.z += xmt[cg][2]; pr.w += xmt[cg][3];
            *(float4*)&pbase[cg * 16] = pr;
        }

        // rotate pipeline
        if (pf) {
#pragma unroll
            for (int cg = 0; cg < 4; cg++) { hpc0[cg] = hpn0[cg]; hpc1[cg] = hpn1[cg]; }
            A2c = A2n;
        }
    }
    __syncthreads();

    // fused Y matmul: Y[root0+..] = [X2|X1](16x128, K interleaved) @ WabT + b1
    {
        float bvy = b1[w * 16 + m];
        f32x4 c = {bvy, bvy, bvy, bvy};
        const bf16x8* brow = (const bf16x8*)(WabT + (size_t)(w * 16 + m) * 128);
#pragma unroll
        for (int kh = 0; kh < 4; kh++) {
            bf16x8 a = *(const bf16x8*)&x2x1[m][kh * 32 + q * 8];
            c = __builtin_amdgcn_mfma_f32_16x16x32_bf16(a, brow[kh * 4 + q], c, 0, 0, 0);
        }
#pragma unroll
        for (int r = 0; r < 4; r++) {
            int row = root0 + q * 4 + r;
            if (row < R) Y[(size_t)row * 64 + w * 16 + m] = c[r];
        }
    }

    // merge 4 private regions -> Qpart (float4-vectorized)
    float* qp = Qpart + (size_t)grp * (PROWS * 64);
    for (int idx = tid; idx < PROWS * 16; idx += 256) {
        int r = idx >> 4, c4 = (idx & 15) * 4;
        int o = r * PSTR + c4;
        float4 s0 = *(float4*)&part[o];
        float4 s1 = *(float4*)&part[PREG + o];
        float4 s2 = *(float4*)&part[2 * PREG + o];
        float4 s3 = *(float4*)&part[3 * PREG + o];
        float4 v;
        v.x = s0.x + s1.x + s2.x + s3.x;
        v.y = s0.y + s1.y + s2.y + s3.y;
        v.z = s0.z + s1.z + s2.z + s3.z;
        v.w = s0.w + s1.w + s2.w + s3.w;
        *(float4*)&qp[r * 64 + c4] = v;
    }
}

// ---- K_linzout: Z[n] = Qavg @ W1c computed in LDS, then out rows written
// directly: out[i*16 + (n-i)] = Y[i] + Z[n]. Eliminates the Z buffer + a pass.
__global__ __launch_bounds__(256) void k_linzout(
    const float* __restrict__ Qpart, const unsigned short* __restrict__ WcT,
    const float* __restrict__ Y, float4* __restrict__ out, int R, int N)
{
    __shared__ float zb[16 * ZSTR];                 // 16 nodes x 64 cols (stride 68)
    int tid = threadIdx.x, lane = tid & 63, w = tid >> 6, m = lane & 15, q = lane >> 4;
    int row0 = blockIdx.x * 16;
    int n = row0 + m;
    float inv = 0.f;
    int gLo = 0, gHi = -1;
    if (n < N) {
        int lo = n - (S - 1); if (lo < 0) lo = 0;
        int hi = (n < R - 1) ? n : (R - 1);
        inv = 1.f / (float)(hi - lo + 1);
        gLo = lo >> 4; gHi = hi >> 4;
    }
    f32x4 c = {0.f, 0.f, 0.f, 0.f};
    const bf16x8* brow = (const bf16x8*)(WcT + (size_t)(w * 16 + m) * 64);
#pragma unroll
    for (int kh = 0; kh < 2; kh++) {
        int k0 = kh * 32 + q * 8;
        float4 u = {0.f, 0.f, 0.f, 0.f}, v = {0.f, 0.f, 0.f, 0.f};
        for (int g = gLo; g <= gHi; g++) {
            const float* src = Qpart + ((size_t)g * PROWS + (n - g * 16)) * 64 + k0;
            float4 uu = *(const float4*)src, vv = *(const float4*)(src + 4);
            u.x += uu.x; u.y += uu.y; u.z += uu.z; u.w += uu.w;
            v.x += vv.x; v.y += vv.y; v.z += vv.z; v.w += vv.w;
        }
        bf16x8 a = pk8(u.x * inv, u.y * inv, u.z * inv, u.w * inv,
                       v.x * inv, v.y * inv, v.z * inv, v.w * inv);
        c = __builtin_amdgcn_mfma_f32_16x16x32_bf16(a, brow[kh * 4 + q], c, 0, 0, 0);
    }
    // stage Z block: local node row 4q+r, col w*16+m
#pragma unroll
    for (int r = 0; r < 4; r++)
        zb[(q * 4 + r) * ZSTR + w * 16 + m] = c[r];
    __syncthreads();

    // out rows: for each local node nl and window index ii: i = lo(n)+ii,
    // out[i*16 + (n-i)] = Y[i] + Z[n].  iteration it pins nl=it (LDS broadcast).
    const float4* Y4 = (const float4*)Y;
#pragma unroll 4
    for (int it = 0; it < 16; ++it) {
        int nl = it;
        int nn = row0 + nl;
        if (nn >= N) break;
        int d4 = tid & 15, ii = tid >> 4;
        int lo = nn - (S - 1); if (lo < 0) lo = 0;
        int hi = (nn < R - 1) ? nn : (R - 1);
        int i = lo + ii;
        if (i > hi) continue;
        int t = i * 16 + (nn - i);
        float4 yv = Y4[(size_t)i * 16 + d4];
        float4 zv = *(float4*)&zb[nl * ZSTR + d4 * 4];
        float4 o;
        o.x = yv.x + zv.x; o.y = yv.y + zv.y; o.z = yv.z + zv.z; o.w = yv.w + zv.w;
        out[(size_t)t * 16 + d4] = o;
    }
}

extern "C" void kernel_launch(void* const* d_in, const int* in_sizes, int n_in,
                              void* d_out, int out_size, void* d_ws, size_t ws_size,
                              hipStream_t stream) {
    (void)n_in; (void)out_size; (void)ws_size;
    const float* X  = (const float*)d_in[0];
    const float* W0 = (const float*)d_in[1];
    const float* b0 = (const float*)d_in[2];
    const float* W1 = (const float*)d_in[3];
    const float* b1 = (const float*)d_in[4];
    const int* msg_tgt = (const int*)d_in[8];
    const int* msg_src = (const int*)d_in[9];
    const int M = in_sizes[5];           // rootid size = R*S
    const int R = in_sizes[7];           // diag_tuple size
    const int E = in_sizes[8];           // number of tuple-level messages
    const int N = R + S - 1;

    char* p = (char*)d_ws;
    unsigned long long* Q = (unsigned long long*)p; p += (size_t)N * 16;  // [N][2]
    float* Y    = (float*)p;             p += (size_t)R * 64 * 4;
    unsigned short* W0T  = (unsigned short*)p; p += (size_t)4096 * 2;
    unsigned short* WabT = (unsigned short*)p; p += (size_t)8192 * 2;
    unsigned short* WcT  = (unsigned short*)p; p += (size_t)4096 * 2;

    // Qpart lives in d_out (written by k_root, consumed by k_linzout, which
    // then fully overwrites d_out). NG*31*64*4 ~ 14.9 MB << out bytes.
    int NG = (R + G - 1) / G;
    float* Qpart = (float*)d_out;

    hipMemsetAsync(Q, 0, (size_t)N * 16, stream);
    int E2 = E >> 1;                     // edge instances live in the first half
    int CB = (E2 > 16384 ? E2 : 16384);
    k_counts<<<(CB + 255) / 256, 256, 0, stream>>>(msg_tgt, msg_src, Q, E2,
                                                   W0, W1, W0T, WabT, WcT);
    k_root<<<NG, 256, 0, stream>>>(X, b0, W0T, Q, WabT, b1, Y, Qpart, R);
    int NB = (N + 15) / 16;
    k_linzout<<<NB, 256, 0, stream>>>(Qpart, WcT, Y, (float4*)d_out, R, N);
    (void)M;
}

// Round 10
// 272.672 us; speedup vs baseline: 1.0196x; 1.0196x over previous
//
#include <hip/hip_runtime.h>

#define S 16
#define D 64
#define G 16            // roots per k_root block (= one MFMA M-tile for Y)
#define PROWS 31        // G + S - 1 node rows per group
#define PSTR 68         // part row stride in dwords (16B-aligned rows for b128 RMW)
#define PREG 2176       // per-wave part region, dwords (>= 31*68, 16B-aligned)
#define XSTR 136        // x2x1 LDS row stride in bf16 (128 + 8 pad)
#define ZSTR 68         // k_linzout Z staging stride

typedef __attribute__((ext_vector_type(8))) short bf16x8;
typedef __attribute__((ext_vector_type(4))) float f32x4;

union BF8 { unsigned u[4]; bf16x8 v; };

// round-half-up f32->bf16 pack: LOW 16 = x, HIGH 16 = y
__device__ __forceinline__ unsigned pk2bf(float x, float y) {
    unsigned ux = __float_as_uint(x) + 0x8000u;
    unsigned uy = __float_as_uint(y) + 0x8000u;
    return __builtin_amdgcn_perm(uy, ux, 0x07060302);  // {lo: hi16(ux), hi: hi16(uy)}
}
__device__ __forceinline__ bf16x8 pk8(float a, float b, float c, float d,
                                      float e, float f, float g, float h) {
    BF8 t;
    t.u[0] = pk2bf(a, b); t.u[1] = pk2bf(c, d);
    t.u[2] = pk2bf(e, f); t.u[3] = pk2bf(g, h);
    return t.v;
}
// RNE (one-time weight prep only)
__device__ __forceinline__ short f2bf(float f) {
    unsigned u = __float_as_uint(f);
    u += 0x7fffu + ((u >> 16) & 1u);
    return (short)(u >> 16);
}

// ---- K_counts (+ fused weight prep in the first 16384 threads) ----
// Per-EDGE graph adjacency counts: Q[node] = 128-bit row, 4-bit field f
// (bit 4f of {lo,hi}) = count at delta = f - 16. Edge (u, u+delta):
// Qhi[u] field delta, Qlo[u+delta] field 16-delta. Each edge appears
// exactly once in the first half of the message list with msg_tgt%16==0
// (the root i == u instance): u = tgt>>4, delta = src&15.
// NOTE: WabT is stored with the K-dim INTERLEAVED: knew = 2e for X2 rows
// (e<64), knew = 2(e-64)+1 for X1 rows — matching x2x1's (X2,X1) pairs.
__global__ void k_counts(const int* __restrict__ msg_tgt, const int* __restrict__ msg_src,
                         unsigned long long* __restrict__ Q, int E2,
                         const float* __restrict__ W0, const float* __restrict__ W1,
                         unsigned short* __restrict__ W0T, unsigned short* __restrict__ WabT,
                         unsigned short* __restrict__ WcT) {
    int idx = blockIdx.x * 256 + threadIdx.x;
    if (idx < 4096) {
        int d = idx >> 6, k = idx & 63;
        W0T[d * 64 + k] = (unsigned short)f2bf(W0[k * 64 + d]);
    } else if (idx < 12288) {
        int o = idx - 4096; int d = o >> 7, e = o & 127;
        int knew = (e < 64) ? (2 * e) : (2 * (e - 64) + 1);
        WabT[d * 128 + knew] = (unsigned short)f2bf(W1[e * 64 + d]);
    } else if (idx < 16384) {
        int o = idx - 12288; int d = o >> 6, e = o & 63;
        WcT[d * 64 + e] = (unsigned short)f2bf(W1[(128 + e) * 64 + d]);
    }
    if (idx >= E2) return;
    int t = msg_tgt[idx];
    if (t & 15) return;                      // keep only the i==u instance
    int delta = msg_src[idx] & 15;           // v - u, in [1,15]
    int u = t >> 4;
    atomicAdd(&Q[2 * u + 1], 1ull << (4 * delta));
    atomicAdd(&Q[2 * (u + delta)], 1ull << (64 - 4 * delta));
}

// ---- K_root: one WAVE per root. Swapped-operand stage-2 MFMA -> Xmp^T ->
// b128 part RMW (8 DS/root). RMW is done per-cg in the sink phase (transient
// registers only — whole-loop-live RMW state pushes past the 128-VGPR cap
// under launch_bounds(256,4) and spills; so does pipelining b2 across the
// next root's stage-1. This configuration is the measured optimum.)
__global__ __launch_bounds__(256, 4) void k_root(
    const float* __restrict__ X, const float* __restrict__ b0,
    const unsigned short* __restrict__ W0T,
    const unsigned long long* __restrict__ Q,     // [N][2] packed 4-bit adjacency
    const unsigned short* __restrict__ WabT, const float* __restrict__ b1,
    float* __restrict__ Y, float* __restrict__ Qpart, int R)
{
    __shared__ float part[4 * PREG];               // 34816 B, per-wave private regions
    __shared__ unsigned short x2x1[G][XSTR];       // 4352 B
    int grp = blockIdx.x;
    int tid = threadIdx.x, lane = tid & 63, w = tid >> 6, m = lane & 15, q = lane >> 4;
    const ulonglong2* Q2 = (const ulonglong2*)Q;

    // zero own region: 8 x b128 + 1 x b64 (2176 dwords, private per wave)
    {
        float4 z = {0.f, 0.f, 0.f, 0.f};
#pragma unroll
        for (int i = 0; i < 8; i++)
            *(float4*)&part[w * PREG + i * 256 + lane * 4] = z;
        float2 z2 = {0.f, 0.f};
        *(float2*)&part[w * PREG + 2048 + lane * 2] = z2;
    }

    // stage-1 B fragments for all 4 column groups (resident in VGPRs)
    bf16x8 bB[8];
    float bv[4];
#pragma unroll
    for (int cg = 0; cg < 4; cg++) {
        const bf16x8* wr = (const bf16x8*)(W0T + (size_t)(cg * 16 + m) * 64);
        bB[cg * 2] = wr[q]; bB[cg * 2 + 1] = wr[4 + q];
        bv[cg] = b0[cg * 16 + m];
    }

    // hoisted bpermute byte-addresses for the stage-2 gather:
    // lane (q,m) pulls H rows 8q..8q+7 (col m) from lanes (2q,m),(2q+1,m) (mod 64)
    int bp0 = (((2 * q) * 16 + m) & 63) * 4;
    int bp1 = (((2 * q + 1) * 16 + m) & 63) * 4;

    int root0 = grp * G;
    int gmax = R - root0; if (gmax > G) gmax = G;
    const float* Xg = X + (size_t)root0 * S * D;

    float4 xa, xb, xc, xd; ulonglong2 qq;
    if (w < gmax) {
        const float* xr = Xg + ((size_t)w * S + m) * D + q * 8;
        xa = *(const float4*)(xr);
        xb = *(const float4*)(xr + 4);
        xc = *(const float4*)(xr + 32);
        xd = *(const float4*)(xr + 36);
        qq = Q2[(size_t)(root0 + w) + m];          // node j = root + m
    }

    for (int g = w; g < gmax; g += 4) {
        float* pbase = &part[w * PREG + (g + m) * PSTR + 4 * q];

        // prefetch next root for this wave
        float4 nxa, nxb, nxc, nxd; ulonglong2 nqq;
        int gn = g + 4;
        bool pf = (gn < gmax);
        if (pf) {
            const float* xr = Xg + ((size_t)gn * S + m) * D + q * 8;
            nxa = *(const float4*)(xr);
            nxb = *(const float4*)(xr + 4);
            nxc = *(const float4*)(xr + 32);
            nxd = *(const float4*)(xr + 36);
            nqq = Q2[(size_t)(root0 + gn) + m];
        }

        // phase A: H = relu(X_blk @ W0 + b0); pack to bf16 pairs immediately
        bf16x8 a0 = pk8(xa.x, xa.y, xa.z, xa.w, xb.x, xb.y, xb.z, xb.w);
        bf16x8 a1 = pk8(xc.x, xc.y, xc.z, xc.w, xd.x, xd.y, xd.z, xd.w);
        unsigned hp0[4], hp1[4];
#pragma unroll
        for (int cg = 0; cg < 4; cg++) {
            f32x4 c = {bv[cg], bv[cg], bv[cg], bv[cg]};
            c = __builtin_amdgcn_mfma_f32_16x16x32_bf16(a0, bB[cg * 2], c, 0, 0, 0);
            c = __builtin_amdgcn_mfma_f32_16x16x32_bf16(a1, bB[cg * 2 + 1], c, 0, 0, 0);
            hp0[cg] = pk2bf(fmaxf(c[0], 0.f), fmaxf(c[1], 0.f));
            hp1[cg] = pk2bf(fmaxf(c[2], 0.f), fmaxf(c[3], 0.f));
        }

        // stage-2 CNT fragment: row m, k = q*8+j (rows k>=16 zero)
        unsigned long long cw = (qq.y << (4 * m)) | ((qq.x >> (63 - 4 * m)) >> 1);
        unsigned w32 = (q == 0) ? (unsigned)cw : ((q == 1) ? (unsigned)(cw >> 32) : 0u);
        bf16x8 A2 = pk8((float)((w32 >> 0) & 15u),  (float)((w32 >> 4) & 15u),
                        (float)((w32 >> 8) & 15u),  (float)((w32 >> 12) & 15u),
                        (float)((w32 >> 16) & 15u), (float)((w32 >> 20) & 15u),
                        (float)((w32 >> 24) & 15u), (float)((w32 >> 28) & 15u));

        // phase B: ALL 16 bperms issued together
        BF8 b2[4];
#pragma unroll
        for (int cg = 0; cg < 4; cg++) {
            b2[cg].u[0] = __builtin_amdgcn_ds_bpermute(bp0, (int)hp0[cg]);
            b2[cg].u[1] = __builtin_amdgcn_ds_bpermute(bp0, (int)hp1[cg]);
            b2[cg].u[2] = __builtin_amdgcn_ds_bpermute(bp1, (int)hp0[cg]);
            b2[cg].u[3] = __builtin_amdgcn_ds_bpermute(bp1, (int)hp1[cg]);
        }

        // phase C: swapped-operand MFMAs -> Xmp^T. Lane (q,m) reg r holds
        // Xmp[tuple row m][d = cg*16 + 4q + r]  (A2's zero k>=16 rows kill
        // the garbage in b2's A-interpretation lanes q>=2).
        f32x4 xmt[4];
#pragma unroll
        for (int cg = 0; cg < 4; cg++) {
            f32x4 z4 = {0.f, 0.f, 0.f, 0.f};
            xmt[cg] = __builtin_amdgcn_mfma_f32_16x16x32_bf16(b2[cg].v, A2, z4, 0, 0, 0);
        }

        // phase D: unswapped MFMAs (MFMA pipe is idle) for the X2/X1 path:
        // lane (q,m) reg r = Xmp[q*4+r][cg*16+m]
        float ps[4], x1[4];
#pragma unroll
        for (int cg = 0; cg < 4; cg++) {
            f32x4 z4 = {0.f, 0.f, 0.f, 0.f};
            f32x4 xu = __builtin_amdgcn_mfma_f32_16x16x32_bf16(A2, b2[cg].v, z4, 0, 0, 0);
            ps[cg] = (xu[0] + xu[1]) + (xu[2] + xu[3]);
            x1[cg] = xu[0];                       // Xmp[0][cg*16+m] valid at q==0
        }
#pragma unroll
        for (int cg = 0; cg < 4; cg++) ps[cg] += __shfl_xor(ps[cg], 16);
#pragma unroll
        for (int cg = 0; cg < 4; cg++) ps[cg] += __shfl_xor(ps[cg], 32);
        if (q == 0) {
#pragma unroll
            for (int cg = 0; cg < 4; cg++)   // interleaved pair: LOW=X2, HIGH=X1
                *(unsigned*)&x2x1[g][2 * (cg * 16 + m)] =
                    pk2bf(ps[cg] * (1.f / 16.f), x1[cg]);
        }

        // phase E (sink): per-cg b128 RMW — transient registers only
#pragma unroll
        for (int cg = 0; cg < 4; cg++) {
            float4 pr = *(float4*)&pbase[cg * 16];
            pr.x += xmt[cg][0]; pr.y += xmt[cg][1];
            pr.z += xmt[cg][2]; pr.w += xmt[cg][3];
            *(float4*)&pbase[cg * 16] = pr;
        }

        if (pf) { xa = nxa; xb = nxb; xc = nxc; xd = nxd; qq = nqq; }
    }
    __syncthreads();

    // fused Y matmul: Y[root0+..] = [X2|X1](16x128, K interleaved) @ WabT + b1
    {
        float bvy = b1[w * 16 + m];
        f32x4 c = {bvy, bvy, bvy, bvy};
        const bf16x8* brow = (const bf16x8*)(WabT + (size_t)(w * 16 + m) * 128);
#pragma unroll
        for (int kh = 0; kh < 4; kh++) {
            bf16x8 a = *(const bf16x8*)&x2x1[m][kh * 32 + q * 8];
            c = __builtin_amdgcn_mfma_f32_16x16x32_bf16(a, brow[kh * 4 + q], c, 0, 0, 0);
        }
#pragma unroll
        for (int r = 0; r < 4; r++) {
            int row = root0 + q * 4 + r;
            if (row < R) Y[(size_t)row * 64 + w * 16 + m] = c[r];
        }
    }

    // merge 4 private regions -> Qpart (float2-vectorized)
    float* qp = Qpart + (size_t)grp * (PROWS * 64);
    for (int idx = tid; idx < PROWS * 32; idx += 256) {
        int r = idx >> 5, c2 = (idx & 31) * 2;
        int o = r * PSTR + c2;
        float2 s0 = *(float2*)&part[o];
        float2 s1 = *(float2*)&part[PREG + o];
        float2 s2 = *(float2*)&part[2 * PREG + o];
        float2 s3 = *(float2*)&part[3 * PREG + o];
        float2 v;
        v.x = s0.x + s1.x + s2.x + s3.x;
        v.y = s0.y + s1.y + s2.y + s3.y;
        *(float2*)&qp[r * 64 + c2] = v;
    }
}

// ---- K_linzout: Z[n] = Qavg @ W1c computed in LDS, then out rows written
// directly: out[i*16 + (n-i)] = Y[i] + Z[n]. Eliminates the Z buffer + a pass.
__global__ __launch_bounds__(256) void k_linzout(
    const float* __restrict__ Qpart, const unsigned short* __restrict__ WcT,
    const float* __restrict__ Y, float4* __restrict__ out, int R, int N)
{
    __shared__ float zb[16 * ZSTR];                 // 16 nodes x 64 cols (stride 68)
    int tid = threadIdx.x, lane = tid & 63, w = tid >> 6, m = lane & 15, q = lane >> 4;
    int row0 = blockIdx.x * 16;
    int n = row0 + m;
    float inv = 0.f;
    int gLo = 0, gHi = -1;
    if (n < N) {
        int lo = n - (S - 1); if (lo < 0) lo = 0;
        int hi = (n < R - 1) ? n : (R - 1);
        inv = 1.f / (float)(hi - lo + 1);
        gLo = lo >> 4; gHi = hi >> 4;
    }
    f32x4 c = {0.f, 0.f, 0.f, 0.f};
    const bf16x8* brow = (const bf16x8*)(WcT + (size_t)(w * 16 + m) * 64);
#pragma unroll
    for (int kh = 0; kh < 2; kh++) {
        int k0 = kh * 32 + q * 8;
        float4 u = {0.f, 0.f, 0.f, 0.f}, v = {0.f, 0.f, 0.f, 0.f};
        for (int g = gLo; g <= gHi; g++) {
            const float* src = Qpart + ((size_t)g * PROWS + (n - g * 16)) * 64 + k0;
            float4 uu = *(const float4*)src, vv = *(const float4*)(src + 4);
            u.x += uu.x; u.y += uu.y; u.z += uu.z; u.w += uu.w;
            v.x += vv.x; v.y += vv.y; v.z += vv.z; v.w += vv.w;
        }
        bf16x8 a = pk8(u.x * inv, u.y * inv, u.z * inv, u.w * inv,
                       v.x * inv, v.y * inv, v.z * inv, v.w * inv);
        c = __builtin_amdgcn_mfma_f32_16x16x32_bf16(a, brow[kh * 4 + q], c, 0, 0, 0);
    }
    // stage Z block: local node row 4q+r, col w*16+m
#pragma unroll
    for (int r = 0; r < 4; r++)
        zb[(q * 4 + r) * ZSTR + w * 16 + m] = c[r];
    __syncthreads();

    // out rows: for each local node nl and window index ii: i = lo(n)+ii,
    // out[i*16 + (n-i)] = Y[i] + Z[n].  iteration it pins nl=it (LDS broadcast).
    const float4* Y4 = (const float4*)Y;
#pragma unroll 4
    for (int it = 0; it < 16; ++it) {
        int nl = it;
        int nn = row0 + nl;
        if (nn >= N) break;
        int d4 = tid & 15, ii = tid >> 4;
        int lo = nn - (S - 1); if (lo < 0) lo = 0;
        int hi = (nn < R - 1) ? nn : (R - 1);
        int i = lo + ii;
        if (i > hi) continue;
        int t = i * 16 + (nn - i);
        float4 yv = Y4[(size_t)i * 16 + d4];
        float4 zv = *(float4*)&zb[nl * ZSTR + d4 * 4];
        float4 o;
        o.x = yv.x + zv.x; o.y = yv.y + zv.y; o.z = yv.z + zv.z; o.w = yv.w + zv.w;
        out[(size_t)t * 16 + d4] = o;
    }
}

extern "C" void kernel_launch(void* const* d_in, const int* in_sizes, int n_in,
                              void* d_out, int out_size, void* d_ws, size_t ws_size,
                              hipStream_t stream) {
    (void)n_in; (void)out_size; (void)ws_size;
    const float* X  = (const float*)d_in[0];
    const float* W0 = (const float*)d_in[1];
    const float* b0 = (const float*)d_in[2];
    const float* W1 = (const float*)d_in[3];
    const float* b1 = (const float*)d_in[4];
    const int* msg_tgt = (const int*)d_in[8];
    const int* msg_src = (const int*)d_in[9];
    const int M = in_sizes[5];           // rootid size = R*S
    const int R = in_sizes[7];           // diag_tuple size
    const int E = in_sizes[8];           // number of tuple-level messages
    const int N = R + S - 1;

    char* p = (char*)d_ws;
    unsigned long long* Q = (unsigned long long*)p; p += (size_t)N * 16;  // [N][2]
    float* Y    = (float*)p;             p += (size_t)R * 64 * 4;
    unsigned short* W0T  = (unsigned short*)p; p += (size_t)4096 * 2;
    unsigned short* WabT = (unsigned short*)p; p += (size_t)8192 * 2;
    unsigned short* WcT  = (unsigned short*)p; p += (size_t)4096 * 2;

    // Qpart lives in d_out (written by k_root, consumed by k_linzout, which
    // then fully overwrites d_out). NG*31*64*4 ~ 14.9 MB << out bytes.
    int NG = (R + G - 1) / G;
    float* Qpart = (float*)d_out;

    hipMemsetAsync(Q, 0, (size_t)N * 16, stream);
    int E2 = E >> 1;                     // edge instances live in the first half
    int CB = (E2 > 16384 ? E2 : 16384);
    k_counts<<<(CB + 255) / 256, 256, 0, stream>>>(msg_tgt, msg_src, Q, E2,
                                                   W0, W1, W0T, WabT, WcT);
    k_root<<<NG, 256, 0, stream>>>(X, b0, W0T, Q, WabT, b1, Y, Qpart, R);
    int NB = (N + 15) / 16;
    k_linzout<<<NB, 256, 0, stream>>>(Qpart, WcT, Y, (float4*)d_out, R, N);
    (void)M;
}